// Round 5
// baseline (510.913 us; speedup 1.0000x reference)
//
#include <hip/hip_runtime.h>
#include <hip/hip_bf16.h>

typedef unsigned short u16;
typedef unsigned int u32;
typedef __bf16 bf16x8 __attribute__((ext_vector_type(8)));
typedef float f32x4 __attribute__((ext_vector_type(4)));
typedef unsigned int u32x4 __attribute__((ext_vector_type(4)));

// ---------- helpers ----------
__device__ __forceinline__ float bf2f(u16 u) {
    u32 x = ((u32)u) << 16;
    return __builtin_bit_cast(float, x);
}
__device__ __forceinline__ u16 f2bf(float f) {
    u32 x = __builtin_bit_cast(u32, f);
    u32 r = (x + 0x7fffu + ((x >> 16) & 1u)) >> 16;  // RNE
    return (u16)r;
}
// delu(x) = 10*relu(x) + exp(10*min(x,0)) = x>0 ? 10x+1 : exp(10x)
__device__ __forceinline__ float delu(float x) {
    return x > 0.f ? fmaf(10.f, x, 1.f) : __expf(10.f * x);
}

#define KBAR do { __builtin_amdgcn_s_barrier(); asm volatile("" ::: "memory"); } while (0)
#define WAITV4 asm volatile("s_waitcnt vmcnt(4)" ::: "memory")
#define WAITV5 asm volatile("s_waitcnt vmcnt(5)" ::: "memory")
#define WAITV0 asm volatile("s_waitcnt vmcnt(0)" ::: "memory")

#define GLOAD16(gp, lp) __builtin_amdgcn_global_load_lds( \
    (const __attribute__((address_space(1))) u32*)(const void*)(gp), \
    (__attribute__((address_space(3))) u32*)(void*)(lp), 16, 0, 0)

// ---------- kernel A: fp32 -> bf16 for x, qkv_w; zero reduction buffers ----------
__global__ __launch_bounds__(256) void convert_all(
    const float4* __restrict__ x, const float4* __restrict__ wq,
    u16* __restrict__ xb, u16* __restrict__ wqb, float* __restrict__ red)
{
    const int NX = 3145728, NQ = 442368;
    int gid = blockIdx.x * blockDim.x + threadIdx.x;
    if (gid < 9216) red[gid] = 0.f;  // k_sum | kv_diag | l_kv_diag
    int stride = gridDim.x * blockDim.x;
    for (int i = gid; i < NX + NQ; i += stride) {
        const float4* src; u16* dst; int li;
        if (i < NX) { src = x;  dst = xb;  li = i; }
        else        { src = wq; dst = wqb; li = i - NX; }
        float4 f = src[li];
        ushort4 u;
        u.x = f2bf(f.x); u.y = f2bf(f.y); u.z = f2bf(f.z); u.w = f2bf(f.w);
        *(ushort4*)&dst[4 * (size_t)li] = u;
    }
}

// ============================================================================
// kernel B (fused): per block = one (m-tile of 128 rows, head hh).
// Computes q,k,v 128x64 tiles as one 128x192 virtual tile (cols: q|k|v).
// Epilogue: delu(q) -> nt-store to qd; delu(k),v,delu(y) -> k_sum / kv_diag /
// l_kv_diag partials -> LDS -> atomics. k,v never touch global memory.
// ============================================================================
__device__ __forceinline__ void stage_qkvf(
    const u16* __restrict__ A, const u16* __restrict__ Bt,
    int m0, int hh, int kt, u16* __restrict__ buf, int wave, int lane)
{
    // A: 128 rows x 32k -> 8 chunks of 1KB; this wave does chunks {wave, wave+4}
#pragma unroll
    for (int it = 0; it < 2; ++it) {
        int c   = wave + 4 * it;
        int q_  = c >> 1;                  // k-quad
        int row = ((c & 1) << 6) + lane;
        const u16* ga = A + (size_t)(m0 + row) * 768 + kt + q_ * 8;
        GLOAD16(ga, &buf[c * 512]);
    }
    // B: 192 virtual rows (rg=0:q,1:k,2:v -> Bt row rg*768 + hh*64 + lane),
    // k-quad = wave. LDS layout [quad][vrow<192][8]: chunk (wave*3+rg).
#pragma unroll
    for (int rg = 0; rg < 3; ++rg) {
        const u16* gb = Bt + (size_t)(rg * 768 + hh * 64 + lane) * 768 + kt + wave * 8;
        GLOAD16(gb, &buf[4096 + (wave * 3 + rg) * 512]);
    }
}

__device__ __forceinline__ void compute_qkvf(
    const u16* __restrict__ buf, int wm, int quad, int r, f32x4 acc[2][12])
{
    const u16* ldsA = buf;
    const u16* ldsB = buf + 4096;
    bf16x8 af[2];
#pragma unroll
    for (int i = 0; i < 2; ++i)
        af[i] = *(const bf16x8*)&ldsA[quad * 1024 + (wm * 32 + i * 16 + r) * 8];
#pragma unroll
    for (int j = 0; j < 12; ++j) {
        bf16x8 bf_ = *(const bf16x8*)&ldsB[quad * 1536 + (j * 16 + r) * 8];
        acc[0][j] = __builtin_amdgcn_mfma_f32_16x16x32_bf16(af[0], bf_, acc[0][j], 0, 0, 0);
        acc[1][j] = __builtin_amdgcn_mfma_f32_16x16x32_bf16(af[1], bf_, acc[1][j], 0, 0, 0);
    }
}

__global__ __launch_bounds__(256) void gemm_qkvf(
    const u16* __restrict__ A, const u16* __restrict__ Bt,
    const float* __restrict__ y, u16* __restrict__ qd,
    float* __restrict__ ksum, float* __restrict__ kvd, float* __restrict__ lkvd)
{
    const int l = blockIdx.x;                 // 1536 blocks
    const int xcd = l & 7, s = l >> 3;        // 192 per xcd
    const int ml = s & 15, hh = s >> 4;       // ml fast (16 m-tiles band), head slow
    const int m0 = (xcd * 16 + ml) * 128;
    const int b  = m0 >> 12;

    // LDS: 2 x (A 8KB + B 12KB) = 40 KB
    __shared__ __align__(16) u16 smem[20480];
    u16* buf0 = smem;
    u16* buf1 = smem + 10240;

    const int tid  = threadIdx.x;
    const int lane = tid & 63;
    const int wave = tid >> 6;
    const int quad = lane >> 4, r = lane & 15;
    const int wm = wave;                      // wave = 32-row slice

    f32x4 acc[2][12];
#pragma unroll
    for (int i = 0; i < 2; ++i)
#pragma unroll
        for (int j = 0; j < 12; ++j) acc[i][j] = (f32x4)0.f;

    stage_qkvf(A, Bt, m0, hh, 0, buf0, wave, lane);
    int kt = 0;
    for (; kt + 64 < 768; kt += 64) {
        stage_qkvf(A, Bt, m0, hh, kt + 32, buf1, wave, lane);
        WAITV5; KBAR;
        compute_qkvf(buf0, wm, quad, r, acc);
        KBAR;
        stage_qkvf(A, Bt, m0, hh, kt + 64, buf0, wave, lane);
        WAITV5; KBAR;
        compute_qkvf(buf1, wm, quad, r, acc);
        KBAR;
    }
    stage_qkvf(A, Bt, m0, hh, 736, buf1, wave, lane);
    WAITV5; KBAR;
    compute_qkvf(buf0, wm, quad, r, acc);
    KBAR;
    WAITV0; KBAR;
    compute_qkvf(buf1, wm, quad, r, acc);
    KBAR;

    // -------- epilogue --------
    const int hbase = hh * 64;
    u16* qlds = smem;                         // 128 rows x 72 u16 (18432 B)
    float* redl = (float*)(smem + 9216 * 2);  // after qlds: [wave][3][4][16] f32 (3072 B)

    // q: delu -> LDS (row stride 72 u16 keeps 16B-aligned rows, ~4-way banks)
#pragma unroll
    for (int i = 0; i < 2; ++i)
#pragma unroll
        for (int jj = 0; jj < 4; ++jj)
#pragma unroll
            for (int rr = 0; rr < 4; ++rr) {
                int rl = wm * 32 + i * 16 + quad * 4 + rr;
                qlds[rl * 72 + jj * 16 + r] = f2bf(delu(acc[i][jj][rr]));
            }
    // reductions in fp32: k frag = acc[i][4+jj], v frag = acc[i][8+jj] (same row,d)
    float pk[4] = {0,0,0,0}, pkv[4] = {0,0,0,0}, pl[4] = {0,0,0,0};
#pragma unroll
    for (int i = 0; i < 2; ++i)
#pragma unroll
        for (int jj = 0; jj < 4; ++jj)
#pragma unroll
            for (int rr = 0; rr < 4; ++rr) {
                int rl = wm * 32 + i * 16 + quad * 4 + rr;
                float kv_ = delu(acc[i][4 + jj][rr]);
                float vv  = acc[i][8 + jj][rr];
                float yv  = delu(y[(size_t)(m0 + rl) * 768 + hbase + jj * 16 + r]);
                pk[jj]  += kv_;
                pkv[jj]  = fmaf(kv_, vv, pkv[jj]);
                pl[jj]   = fmaf(yv, vv, pl[jj]);
            }
#pragma unroll
    for (int jj = 0; jj < 4; ++jj) {
        pk[jj]  += __shfl_xor(pk[jj], 16);  pk[jj]  += __shfl_xor(pk[jj], 32);
        pkv[jj] += __shfl_xor(pkv[jj], 16); pkv[jj] += __shfl_xor(pkv[jj], 32);
        pl[jj]  += __shfl_xor(pl[jj], 16);  pl[jj]  += __shfl_xor(pl[jj], 32);
    }
    if (quad == 0) {
#pragma unroll
        for (int jj = 0; jj < 4; ++jj) {
            redl[((wave * 3 + 0) * 4 + jj) * 16 + r] = pk[jj];
            redl[((wave * 3 + 1) * 4 + jj) * 16 + r] = pkv[jj];
            redl[((wave * 3 + 2) * 4 + jj) * 16 + r] = pl[jj];
        }
    }
    __syncthreads();

    // q: LDS -> coalesced nt stores (2 threads per row, 64B each)
    {
        int row = tid >> 1, half = tid & 1;
        const u16* src = &qlds[row * 72 + half * 32];
        u16* dst = &qd[(size_t)(m0 + row) * 768 + hbase + half * 32];
#pragma unroll
        for (int qq = 0; qq < 4; ++qq) {
            u32x4 v_ = *(const u32x4*)&src[qq * 8];
            __builtin_nontemporal_store(v_, (u32x4*)&dst[qq * 8]);
        }
    }
    // cross-wave reduce + atomics (192 threads: tensor x 64 d)
    if (tid < 192) {
        int tens = tid >> 6, d = tid & 63;
        int jj = d >> 4, rl = d & 15;
        float sum = 0.f;
#pragma unroll
        for (int w = 0; w < 4; ++w)
            sum += redl[((w * 3 + tens) * 4 + jj) * 16 + rl];
        int bh = b * 12 + hh;
        if (tens == 0)      atomicAdd(&ksum[bh * 64 + d], sum);
        else if (tens == 1) atomicAdd(&kvd[bh * 64 + d],  sum * 0.125f);
        else                atomicAdd(&lkvd[bh * 64 + d], sum * 0.125f);
    }
}

// ---------- GEMM core (proj): 128x128 tile, BK=32, 2-phase double-buffer ----------
__device__ __forceinline__ void stage_step(
    const u16* __restrict__ A, const u16* __restrict__ Bt,
    int lda, int ldb, int m0, int n0, int kt,
    u16* __restrict__ buf, int wave, int lane)
{
#pragma unroll
    for (int it = 0; it < 2; ++it) {
        int c   = wave + 4 * it;
        int q_  = c >> 1;
        int row = ((c & 1) << 6) + lane;
        const u16* ga = A  + (size_t)(m0 + row) * lda + kt + q_ * 8;
        const u16* gb = Bt + (size_t)(n0 + row) * ldb + kt + q_ * 8;
        GLOAD16(ga, &buf[c * 512]);
        GLOAD16(gb, &buf[4096 + c * 512]);
    }
}

__device__ __forceinline__ void compute_step(
    const u16* __restrict__ buf, int wm, int wn, int quad, int r, f32x4 acc[4][4])
{
    const u16* ldsA = buf;
    const u16* ldsB = buf + 4096;
    bf16x8 af[4], bfr[4];
#pragma unroll
    for (int i = 0; i < 4; ++i)
        af[i] = *(const bf16x8*)&ldsA[quad * 1024 + (wm * 64 + i * 16 + r) * 8];
#pragma unroll
    for (int j = 0; j < 4; ++j)
        bfr[j] = *(const bf16x8*)&ldsB[quad * 1024 + (wn * 64 + j * 16 + r) * 8];
#pragma unroll
    for (int i = 0; i < 4; ++i)
#pragma unroll
        for (int j = 0; j < 4; ++j)
            acc[i][j] = __builtin_amdgcn_mfma_f32_16x16x32_bf16(
                af[i], bfr[j], acc[i][j], 0, 0, 0);
}

__device__ __forceinline__ void gemm_core(
    const u16* __restrict__ A, const u16* __restrict__ Bt,
    int lda, int ldb, int K, int m0, int n0,
    u16* __restrict__ buf0, u16* __restrict__ buf1, f32x4 acc[4][4])
{
    const int tid  = threadIdx.x;
    const int lane = tid & 63;
    const int wave = tid >> 6;
    const int wm = wave >> 1, wn = wave & 1;
    const int quad = lane >> 4, r = lane & 15;

    stage_step(A, Bt, lda, ldb, m0, n0, 0, buf0, wave, lane);
    int kt = 0;
    for (; kt + 64 < K; kt += 64) {
        stage_step(A, Bt, lda, ldb, m0, n0, kt + 32, buf1, wave, lane);
        WAITV4; KBAR;
        compute_step(buf0, wm, wn, quad, r, acc);
        KBAR;
        stage_step(A, Bt, lda, ldb, m0, n0, kt + 64, buf0, wave, lane);
        WAITV4; KBAR;
        compute_step(buf1, wm, wn, quad, r, acc);
        KBAR;
    }
    stage_step(A, Bt, lda, ldb, m0, n0, K - 32, buf1, wave, lane);
    WAITV4; KBAR;
    compute_step(buf0, wm, wn, quad, r, acc);
    KBAR;
    WAITV0; KBAR;
    compute_step(buf1, wm, wn, quad, r, acc);
    KBAR;
}

// ---------- kernel D: fold kv_diag / l_kv_diag into per-batch scaled weights ----------
__global__ __launch_bounds__(256) void scale_weights(
    const float* __restrict__ w1, const float* __restrict__ w2,
    const float* __restrict__ kvd, const float* __restrict__ lkvd,
    u16* __restrict__ w1s, u16* __restrict__ w2s)
{
    const int NITEM = 1179648;  // 2 tensors * 4 batches * 768 * 192 quads
    int gid = blockIdx.x * blockDim.x + threadIdx.x;
    int stride = gridDim.x * blockDim.x;
    for (int i = gid; i < NITEM; i += stride) {
        int t = i / 589824, r = i % 589824;
        int b = r / 147456, rr = r % 147456;
        int o = rr / 192, c = (rr % 192) * 4;
        const float* w = t ? w2 : w1;
        const float* dg = t ? lkvd : kvd;
        u16* dst = t ? w2s : w1s;
        float4 wf = *(const float4*)&w[o * 768 + c];
        float4 sf = *(const float4*)&dg[(b * 12 + (c >> 6)) * 64 + (c & 63)];
        ushort4 u;
        u.x = f2bf(wf.x * sf.x); u.y = f2bf(wf.y * sf.y);
        u.z = f2bf(wf.z * sf.z); u.w = f2bf(wf.w * sf.w);
        *(ushort4*)&dst[(size_t)b * 589824 + o * 768 + c] = u;
    }
}

// ---------- kernel E: q' = q * norm  (bf16, in: qd [16384][768]) ----------
__global__ __launch_bounds__(768) void norm_q(
    const u16* __restrict__ qd, const float* __restrict__ ksum,
    u16* __restrict__ qn)
{
    int row = blockIdx.x;
    int c = threadIdx.x;
    int h = c >> 6, d = c & 63;
    int b = row >> 12;
    int bh = b * 12 + h;
    float qf = bf2f(qd[(size_t)row * 768 + c]);   // q (already delu'd)
    float ks = ksum[bh * 64 + d] + 1e-10f;
    float p = qf * ks;
#pragma unroll
    for (int off = 32; off; off >>= 1) p += __shfl_xor(p, off);
    qn[(size_t)row * 768 + c] = f2bf(qf / p);
}

// ---------- kernel F: projection GEMMs, bias, fp32 out (nt stores) ----------
__global__ __launch_bounds__(256) void gemm_proj(
    const u16* __restrict__ A,
    const u16* __restrict__ W1s, const float* __restrict__ b1, float* __restrict__ O1,
    const u16* __restrict__ W2s, const float* __restrict__ b2, float* __restrict__ O2)
{
    const int l = blockIdx.x;
    const int xcd = l & 7, s = l >> 3;     // 192 blocks per xcd
    const int ml = s & 15, c_ = s >> 4;    // c_ in [0,12): (n,z) combo
    const int nt = c_ % 6, z = c_ / 6;
    const int m0 = (xcd * 16 + ml) * 128, n0 = nt * 128;
    const int b = m0 >> 12;                // batch of this row-block
    const u16* W = (z ? W2s : W1s) + (size_t)b * 589824;
    const float* bias = z ? b2 : b1;
    float* O = z ? O2 : O1;

    __shared__ __align__(16) u16 smem[16384];  // 32 KB: buf0 | buf1 (epi reuse)
    f32x4 acc[4][4] = {};
    gemm_core(A, W, 768, 768, 768, m0, n0, smem, smem + 8192, acc);

    const int tid  = threadIdx.x;
    const int lane = tid & 63;
    const int wave = tid >> 6;
    const int wm = wave >> 1, wn = wave & 1;
    const int l15 = lane & 15, l4 = lane >> 4;
    float* eb = (float*)smem;              // 32 rows x 132 f32 (pad breaks banks)
    const int r_ = tid >> 3, part = tid & 7;
    const int growb = m0 + (r_ & 15) + ((r_ >> 4) << 6);
    f32x4 bq[4];
#pragma unroll
    for (int q = 0; q < 4; ++q)
        bq[q] = *(const f32x4*)&bias[n0 + part * 16 + q * 4];
#pragma unroll
    for (int i = 0; i < 4; ++i) {
        if (i) __syncthreads();
#pragma unroll
        for (int j = 0; j < 4; ++j) {
            const int col = wn * 64 + j * 16 + l15;
            const int lr0 = wm * 16 + l4 * 4;
#pragma unroll
            for (int rr = 0; rr < 4; ++rr)
                eb[(lr0 + rr) * 132 + col] = acc[i][j][rr];
        }
        __syncthreads();
        float* orow = O + (size_t)(growb + i * 16) * 768 + n0 + part * 16;
        const float* lrow = eb + r_ * 132 + part * 16;
#pragma unroll
        for (int q = 0; q < 4; ++q) {
            f32x4 v = *(const f32x4*)&lrow[q * 4] + bq[q];
            __builtin_nontemporal_store(v, (f32x4*)&orow[q * 4]);
        }
    }
}

extern "C" void kernel_launch(void* const* d_in, const int* in_sizes, int n_in,
                              void* d_out, int out_size, void* d_ws, size_t ws_size,
                              hipStream_t stream)
{
    const float* x     = (const float*)d_in[0];
    const float* y     = (const float*)d_in[1];
    const float* qkv_w = (const float*)d_in[2];
    const float* w1    = (const float*)d_in[3];
    const float* b1    = (const float*)d_in[4];
    const float* w2    = (const float*)d_in[5];
    const float* b2    = (const float*)d_in[6];
    float* out = (float*)d_out;

    char* ws = (char*)d_ws;
    // ws layout (34.64 MB, same footprint as before):
    //   xb  @ 0         : 25,165,824  (x bf16; dead after gemm_qkvf -> reused as qn)
    //   wqb @ 25165824  :  3,538,944  (qkv_w bf16; dead after gemm_qkvf)
    //   w1s @ 25165824  :  4,718,592  (over dead wqb)
    //   w2s @ 29884416  :  4,718,592
    //   red @ 34603008  :     36,864  (k_sum | kv_diag | l_kv_diag)
    // qd (delu'd q, bf16 [16384][768], 25.2 MB) lives in d_out; dead before
    // gemm_proj overwrites d_out (gemm_proj reads qn@ws only).
    u16* xb   = (u16*)(ws);
    u16* wqb  = (u16*)(ws + 25165824);
    u16* w1s  = (u16*)(ws + 25165824);
    u16* w2s  = (u16*)(ws + 29884416);
    float* red  = (float*)(ws + 34603008);
    float* ksum = red;
    float* kvd  = red + 3072;
    float* lkvd = red + 6144;
    u16* qd = (u16*)d_out;     // 25.2 MB <= out_size
    u16* qn = xb;              // q' over dead xb

    convert_all<<<4096, 256, 0, stream>>>(
        (const float4*)x, (const float4*)qkv_w, xb, wqb, red);

    gemm_qkvf<<<1536, 256, 0, stream>>>(xb, wqb, y, qd, ksum, kvd, lkvd);

    scale_weights<<<1152, 256, 0, stream>>>(w1, w2, kvd, lkvd, w1s, w2s);

    norm_q<<<16384, 768, 0, stream>>>(qd, ksum, qn);

    gemm_proj<<<1536, 256, 0, stream>>>(
        qn, w1s, b1, out, w2s, b2, out + 12582912);
}

// Round 6
// 428.057 us; speedup vs baseline: 1.1936x; 1.1936x over previous
//
#include <hip/hip_runtime.h>
#include <hip/hip_bf16.h>

typedef unsigned short u16;
typedef unsigned int u32;
typedef __bf16 bf16x8 __attribute__((ext_vector_type(8)));
typedef float f32x4 __attribute__((ext_vector_type(4)));
typedef unsigned int u32x4 __attribute__((ext_vector_type(4)));

// ---------- helpers ----------
__device__ __forceinline__ float bf2f(u16 u) {
    u32 x = ((u32)u) << 16;
    return __builtin_bit_cast(float, x);
}
__device__ __forceinline__ u16 f2bf(float f) {
    u32 x = __builtin_bit_cast(u32, f);
    u32 r = (x + 0x7fffu + ((x >> 16) & 1u)) >> 16;  // RNE
    return (u16)r;
}
// delu(x) = 10*relu(x) + exp(10*min(x,0)) = x>0 ? 10x+1 : exp(10x)
__device__ __forceinline__ float delu(float x) {
    return x > 0.f ? fmaf(10.f, x, 1.f) : __expf(10.f * x);
}

#define KBAR do { __builtin_amdgcn_s_barrier(); asm volatile("" ::: "memory"); } while (0)
#define WAITV4 asm volatile("s_waitcnt vmcnt(4)" ::: "memory")
#define WAITV5 asm volatile("s_waitcnt vmcnt(5)" ::: "memory")
#define WAITV0 asm volatile("s_waitcnt vmcnt(0)" ::: "memory")

#define GLOAD16(gp, lp) __builtin_amdgcn_global_load_lds( \
    (const __attribute__((address_space(1))) u32*)(const void*)(gp), \
    (__attribute__((address_space(3))) u32*)(void*)(lp), 16, 0, 0)

// ---------- kernel A: fp32 -> bf16 for x, qkv_w; zero reduction buffers ----------
__global__ __launch_bounds__(256) void convert_all(
    const float4* __restrict__ x, const float4* __restrict__ wq,
    u16* __restrict__ xb, u16* __restrict__ wqb, float* __restrict__ red)
{
    const int NX = 3145728, NQ = 442368;
    int gid = blockIdx.x * blockDim.x + threadIdx.x;
    if (gid < 9216) red[gid] = 0.f;  // k_sum | kv_diag | l_kv_diag
    int stride = gridDim.x * blockDim.x;
    for (int i = gid; i < NX + NQ; i += stride) {
        const float4* src; u16* dst; int li;
        if (i < NX) { src = x;  dst = xb;  li = i; }
        else        { src = wq; dst = wqb; li = i - NX; }
        float4 f = src[li];
        ushort4 u;
        u.x = f2bf(f.x); u.y = f2bf(f.y); u.z = f2bf(f.z); u.w = f2bf(f.w);
        *(ushort4*)&dst[4 * (size_t)li] = u;
    }
}

// ============================================================================
// kernel B (fused): per block = one (m-tile of 128 rows, head hh).
// Computes q,k,v 128x64 tiles as one 128x192 virtual tile (cols: q|k|v).
// Epilogue: delu(q) -> store to qd; delu(k),v,delu(y) -> k_sum / kv_diag /
// l_kv_diag partials -> LDS -> atomics. k,v never touch global memory.
// ============================================================================
__device__ __forceinline__ void stage_qkvf(
    const u16* __restrict__ A, const u16* __restrict__ Bt,
    int m0, int hh, int kt, u16* __restrict__ buf, int wave, int lane)
{
    // A: 128 rows x 32k -> 8 chunks of 1KB; this wave does chunks {wave, wave+4}
#pragma unroll
    for (int it = 0; it < 2; ++it) {
        int c   = wave + 4 * it;
        int q_  = c >> 1;                  // k-quad
        int row = ((c & 1) << 6) + lane;
        const u16* ga = A + (size_t)(m0 + row) * 768 + kt + q_ * 8;
        GLOAD16(ga, &buf[c * 512]);
    }
    // B: 192 virtual rows (rg=0:q,1:k,2:v -> Bt row rg*768 + hh*64 + lane),
    // k-quad = wave. LDS layout [quad][vrow<192][8]: chunk (wave*3+rg).
#pragma unroll
    for (int rg = 0; rg < 3; ++rg) {
        const u16* gb = Bt + (size_t)(rg * 768 + hh * 64 + lane) * 768 + kt + wave * 8;
        GLOAD16(gb, &buf[4096 + (wave * 3 + rg) * 512]);
    }
}

__device__ __forceinline__ void compute_qkvf(
    const u16* __restrict__ buf, int wm, int quad, int r, f32x4 acc[2][12])
{
    const u16* ldsA = buf;
    const u16* ldsB = buf + 4096;
    bf16x8 af[2];
#pragma unroll
    for (int i = 0; i < 2; ++i)
        af[i] = *(const bf16x8*)&ldsA[quad * 1024 + (wm * 32 + i * 16 + r) * 8];
#pragma unroll
    for (int j = 0; j < 12; ++j) {
        bf16x8 bf_ = *(const bf16x8*)&ldsB[quad * 1536 + (j * 16 + r) * 8];
        acc[0][j] = __builtin_amdgcn_mfma_f32_16x16x32_bf16(af[0], bf_, acc[0][j], 0, 0, 0);
        acc[1][j] = __builtin_amdgcn_mfma_f32_16x16x32_bf16(af[1], bf_, acc[1][j], 0, 0, 0);
    }
}

__global__ __launch_bounds__(256) void gemm_qkvf(
    const u16* __restrict__ A, const u16* __restrict__ Bt,
    const float* __restrict__ y, u16* __restrict__ qd,
    float* __restrict__ ksum, float* __restrict__ kvd, float* __restrict__ lkvd)
{
    const int l = blockIdx.x;                 // 1536 blocks
    const int xcd = l & 7, s = l >> 3;        // 192 per xcd
    const int ml = s & 15, hh = s >> 4;       // ml fast (16 m-tiles band), head slow
    const int m0 = (xcd * 16 + ml) * 128;
    const int b  = m0 >> 12;

    // LDS: 2 x (A 8KB + B 12KB) = 40 KB
    __shared__ __align__(16) u16 smem[20480];
    u16* buf0 = smem;
    u16* buf1 = smem + 10240;

    const int tid  = threadIdx.x;
    const int lane = tid & 63;
    const int wave = tid >> 6;
    const int quad = lane >> 4, r = lane & 15;
    const int wm = wave;                      // wave = 32-row slice

    f32x4 acc[2][12];
#pragma unroll
    for (int i = 0; i < 2; ++i)
#pragma unroll
        for (int j = 0; j < 12; ++j) acc[i][j] = (f32x4)0.f;

    stage_qkvf(A, Bt, m0, hh, 0, buf0, wave, lane);
    int kt = 0;
    for (; kt + 64 < 768; kt += 64) {
        stage_qkvf(A, Bt, m0, hh, kt + 32, buf1, wave, lane);
        WAITV5; KBAR;
        compute_qkvf(buf0, wm, quad, r, acc);
        KBAR;
        stage_qkvf(A, Bt, m0, hh, kt + 64, buf0, wave, lane);
        WAITV5; KBAR;
        compute_qkvf(buf1, wm, quad, r, acc);
        KBAR;
    }
    stage_qkvf(A, Bt, m0, hh, 736, buf1, wave, lane);
    WAITV5; KBAR;
    compute_qkvf(buf0, wm, quad, r, acc);
    KBAR;
    WAITV0; KBAR;
    compute_qkvf(buf1, wm, quad, r, acc);
    KBAR;

    // -------- epilogue --------
    const int hbase = hh * 64;
    u16* qlds = smem;                         // 128 rows x 72 u16 (18432 B)
    float* redl = (float*)(smem + 9216 * 2);  // after qlds: [wave][3][4][16] f32 (3072 B)

    // q: delu -> LDS (row stride 72 u16 keeps 16B-aligned rows, ~4-way banks)
#pragma unroll
    for (int i = 0; i < 2; ++i)
#pragma unroll
        for (int jj = 0; jj < 4; ++jj)
#pragma unroll
            for (int rr = 0; rr < 4; ++rr) {
                int rl = wm * 32 + i * 16 + quad * 4 + rr;
                qlds[rl * 72 + jj * 16 + r] = f2bf(delu(acc[i][jj][rr]));
            }
    // reductions in fp32: k frag = acc[i][4+jj], v frag = acc[i][8+jj] (same row,d)
    float pk[4] = {0,0,0,0}, pkv[4] = {0,0,0,0}, pl[4] = {0,0,0,0};
#pragma unroll
    for (int i = 0; i < 2; ++i)
#pragma unroll
        for (int jj = 0; jj < 4; ++jj)
#pragma unroll
            for (int rr = 0; rr < 4; ++rr) {
                int rl = wm * 32 + i * 16 + quad * 4 + rr;
                float kv_ = delu(acc[i][4 + jj][rr]);
                float vv  = acc[i][8 + jj][rr];
                float yv  = delu(y[(size_t)(m0 + rl) * 768 + hbase + jj * 16 + r]);
                pk[jj]  += kv_;
                pkv[jj]  = fmaf(kv_, vv, pkv[jj]);
                pl[jj]   = fmaf(yv, vv, pl[jj]);
            }
#pragma unroll
    for (int jj = 0; jj < 4; ++jj) {
        pk[jj]  += __shfl_xor(pk[jj], 16);  pk[jj]  += __shfl_xor(pk[jj], 32);
        pkv[jj] += __shfl_xor(pkv[jj], 16); pkv[jj] += __shfl_xor(pkv[jj], 32);
        pl[jj]  += __shfl_xor(pl[jj], 16);  pl[jj]  += __shfl_xor(pl[jj], 32);
    }
    if (quad == 0) {
#pragma unroll
        for (int jj = 0; jj < 4; ++jj) {
            redl[((wave * 3 + 0) * 4 + jj) * 16 + r] = pk[jj];
            redl[((wave * 3 + 1) * 4 + jj) * 16 + r] = pkv[jj];
            redl[((wave * 3 + 2) * 4 + jj) * 16 + r] = pl[jj];
        }
    }
    __syncthreads();

    // q: LDS -> coalesced stores (2 threads per row, 64B each)
    {
        int row = tid >> 1, half = tid & 1;
        const u16* src = &qlds[row * 72 + half * 32];
        u16* dst = &qd[(size_t)(m0 + row) * 768 + hbase + half * 32];
#pragma unroll
        for (int qq = 0; qq < 4; ++qq) {
            u32x4 v_ = *(const u32x4*)&src[qq * 8];
            *(u32x4*)&dst[qq * 8] = v_;
        }
    }
    // cross-wave reduce + atomics (192 threads: tensor x 64 d)
    if (tid < 192) {
        int tens = tid >> 6, d = tid & 63;
        int jj = d >> 4, rl = d & 15;
        float sum = 0.f;
#pragma unroll
        for (int w = 0; w < 4; ++w)
            sum += redl[((w * 3 + tens) * 4 + jj) * 16 + rl];
        int bh = b * 12 + hh;
        if (tens == 0)      atomicAdd(&ksum[bh * 64 + d], sum);
        else if (tens == 1) atomicAdd(&kvd[bh * 64 + d],  sum * 0.125f);
        else                atomicAdd(&lkvd[bh * 64 + d], sum * 0.125f);
    }
}

// ---------- GEMM core (proj): 128x128 tile, BK=32, 2-phase double-buffer ----------
__device__ __forceinline__ void stage_step(
    const u16* __restrict__ A, const u16* __restrict__ Bt,
    int lda, int ldb, int m0, int n0, int kt,
    u16* __restrict__ buf, int wave, int lane)
{
#pragma unroll
    for (int it = 0; it < 2; ++it) {
        int c   = wave + 4 * it;
        int q_  = c >> 1;
        int row = ((c & 1) << 6) + lane;
        const u16* ga = A  + (size_t)(m0 + row) * lda + kt + q_ * 8;
        const u16* gb = Bt + (size_t)(n0 + row) * ldb + kt + q_ * 8;
        GLOAD16(ga, &buf[c * 512]);
        GLOAD16(gb, &buf[4096 + c * 512]);
    }
}

__device__ __forceinline__ void compute_step(
    const u16* __restrict__ buf, int wm, int wn, int quad, int r, f32x4 acc[4][4])
{
    const u16* ldsA = buf;
    const u16* ldsB = buf + 4096;
    bf16x8 af[4], bfr[4];
#pragma unroll
    for (int i = 0; i < 4; ++i)
        af[i] = *(const bf16x8*)&ldsA[quad * 1024 + (wm * 64 + i * 16 + r) * 8];
#pragma unroll
    for (int j = 0; j < 4; ++j)
        bfr[j] = *(const bf16x8*)&ldsB[quad * 1024 + (wn * 64 + j * 16 + r) * 8];
#pragma unroll
    for (int i = 0; i < 4; ++i)
#pragma unroll
        for (int j = 0; j < 4; ++j)
            acc[i][j] = __builtin_amdgcn_mfma_f32_16x16x32_bf16(
                af[i], bfr[j], acc[i][j], 0, 0, 0);
}

__device__ __forceinline__ void gemm_core(
    const u16* __restrict__ A, const u16* __restrict__ Bt,
    int lda, int ldb, int K, int m0, int n0,
    u16* __restrict__ buf0, u16* __restrict__ buf1, f32x4 acc[4][4])
{
    const int tid  = threadIdx.x;
    const int lane = tid & 63;
    const int wave = tid >> 6;
    const int wm = wave >> 1, wn = wave & 1;
    const int quad = lane >> 4, r = lane & 15;

    stage_step(A, Bt, lda, ldb, m0, n0, 0, buf0, wave, lane);
    int kt = 0;
    for (; kt + 64 < K; kt += 64) {
        stage_step(A, Bt, lda, ldb, m0, n0, kt + 32, buf1, wave, lane);
        WAITV4; KBAR;
        compute_step(buf0, wm, wn, quad, r, acc);
        KBAR;
        stage_step(A, Bt, lda, ldb, m0, n0, kt + 64, buf0, wave, lane);
        WAITV4; KBAR;
        compute_step(buf1, wm, wn, quad, r, acc);
        KBAR;
    }
    stage_step(A, Bt, lda, ldb, m0, n0, K - 32, buf1, wave, lane);
    WAITV4; KBAR;
    compute_step(buf0, wm, wn, quad, r, acc);
    KBAR;
    WAITV0; KBAR;
    compute_step(buf1, wm, wn, quad, r, acc);
    KBAR;
}

// ---------- kernel D: fold kv_diag / l_kv_diag into per-batch scaled weights ----------
__global__ __launch_bounds__(256) void scale_weights(
    const float* __restrict__ w1, const float* __restrict__ w2,
    const float* __restrict__ kvd, const float* __restrict__ lkvd,
    u16* __restrict__ w1s, u16* __restrict__ w2s)
{
    const int NITEM = 1179648;  // 2 tensors * 4 batches * 768 * 192 quads
    int gid = blockIdx.x * blockDim.x + threadIdx.x;
    int stride = gridDim.x * blockDim.x;
    for (int i = gid; i < NITEM; i += stride) {
        int t = i / 589824, r = i % 589824;
        int b = r / 147456, rr = r % 147456;
        int o = rr / 192, c = (rr % 192) * 4;
        const float* w = t ? w2 : w1;
        const float* dg = t ? lkvd : kvd;
        u16* dst = t ? w2s : w1s;
        float4 wf = *(const float4*)&w[o * 768 + c];
        float4 sf = *(const float4*)&dg[(b * 12 + (c >> 6)) * 64 + (c & 63)];
        ushort4 u;
        u.x = f2bf(wf.x * sf.x); u.y = f2bf(wf.y * sf.y);
        u.z = f2bf(wf.z * sf.z); u.w = f2bf(wf.w * sf.w);
        *(ushort4*)&dst[(size_t)b * 589824 + o * 768 + c] = u;
    }
}

// ---------- kernel E: q' = q * norm  (bf16, in: qd [16384][768]) ----------
__global__ __launch_bounds__(768) void norm_q(
    const u16* __restrict__ qd, const float* __restrict__ ksum,
    u16* __restrict__ qn)
{
    int row = blockIdx.x;
    int c = threadIdx.x;
    int h = c >> 6, d = c & 63;
    int b = row >> 12;
    int bh = b * 12 + h;
    float qf = bf2f(qd[(size_t)row * 768 + c]);   // q (already delu'd)
    float ks = ksum[bh * 64 + d] + 1e-10f;
    float p = qf * ks;
#pragma unroll
    for (int off = 32; off; off >>= 1) p += __shfl_xor(p, off);
    qn[(size_t)row * 768 + c] = f2bf(qf / p);
}

// ---------- kernel F: projection GEMMs, bias, fp32 out ----------
__global__ __launch_bounds__(256) void gemm_proj(
    const u16* __restrict__ A,
    const u16* __restrict__ W1s, const float* __restrict__ b1, float* __restrict__ O1,
    const u16* __restrict__ W2s, const float* __restrict__ b2, float* __restrict__ O2)
{
    const int l = blockIdx.x;
    const int xcd = l & 7, s = l >> 3;     // 192 blocks per xcd
    const int ml = s & 15, c_ = s >> 4;    // c_ in [0,12): (n,z) combo
    const int nt = c_ % 6, z = c_ / 6;
    const int m0 = (xcd * 16 + ml) * 128, n0 = nt * 128;
    const int b = m0 >> 12;                // batch of this row-block
    const u16* W = (z ? W2s : W1s) + (size_t)b * 589824;
    const float* bias = z ? b2 : b1;
    float* O = z ? O2 : O1;

    __shared__ __align__(16) u16 smem[16384];  // 32 KB: buf0 | buf1 (epi reuse)
    f32x4 acc[4][4] = {};
    gemm_core(A, W, 768, 768, 768, m0, n0, smem, smem + 8192, acc);

    const int tid  = threadIdx.x;
    const int lane = tid & 63;
    const int wave = tid >> 6;
    const int wm = wave >> 1, wn = wave & 1;
    const int l15 = lane & 15, l4 = lane >> 4;
    float* eb = (float*)smem;              // 32 rows x 132 f32 (pad breaks banks)
    const int r_ = tid >> 3, part = tid & 7;
    const int growb = m0 + (r_ & 15) + ((r_ >> 4) << 6);
    f32x4 bq[4];
#pragma unroll
    for (int q = 0; q < 4; ++q)
        bq[q] = *(const f32x4*)&bias[n0 + part * 16 + q * 4];
#pragma unroll
    for (int i = 0; i < 4; ++i) {
        if (i) __syncthreads();
#pragma unroll
        for (int j = 0; j < 4; ++j) {
            const int col = wn * 64 + j * 16 + l15;
            const int lr0 = wm * 16 + l4 * 4;
#pragma unroll
            for (int rr = 0; rr < 4; ++rr)
                eb[(lr0 + rr) * 132 + col] = acc[i][j][rr];
        }
        __syncthreads();
        float* orow = O + (size_t)(growb + i * 16) * 768 + n0 + part * 16;
        const float* lrow = eb + r_ * 132 + part * 16;
#pragma unroll
        for (int q = 0; q < 4; ++q) {
            f32x4 v = *(const f32x4*)&lrow[q * 4] + bq[q];
            *(f32x4*)&orow[q * 4] = v;
        }
    }
}

extern "C" void kernel_launch(void* const* d_in, const int* in_sizes, int n_in,
                              void* d_out, int out_size, void* d_ws, size_t ws_size,
                              hipStream_t stream)
{
    const float* x     = (const float*)d_in[0];
    const float* y     = (const float*)d_in[1];
    const float* qkv_w = (const float*)d_in[2];
    const float* w1    = (const float*)d_in[3];
    const float* b1    = (const float*)d_in[4];
    const float* w2    = (const float*)d_in[5];
    const float* b2    = (const float*)d_in[6];
    float* out = (float*)d_out;

    char* ws = (char*)d_ws;
    // ws layout (34.64 MB):
    //   xb  @ 0         : 25,165,824  (x bf16; dead after gemm_qkvf -> reused as qn)
    //   wqb @ 25165824  :  3,538,944  (qkv_w bf16; dead after gemm_qkvf)
    //   w1s @ 25165824  :  4,718,592  (over dead wqb)
    //   w2s @ 29884416  :  4,718,592
    //   red @ 34603008  :     36,864  (k_sum | kv_diag | l_kv_diag)
    // qd (delu'd q, bf16 [16384][768], 25.2 MB) lives in d_out; dead before
    // gemm_proj overwrites d_out (gemm_proj reads qn@ws only).
    u16* xb   = (u16*)(ws);
    u16* wqb  = (u16*)(ws + 25165824);
    u16* w1s  = (u16*)(ws + 25165824);
    u16* w2s  = (u16*)(ws + 29884416);
    float* red  = (float*)(ws + 34603008);
    float* ksum = red;
    float* kvd  = red + 3072;
    float* lkvd = red + 6144;
    u16* qd = (u16*)d_out;     // 25.2 MB <= out_size
    u16* qn = xb;              // q' over dead xb

    convert_all<<<4096, 256, 0, stream>>>(
        (const float4*)x, (const float4*)qkv_w, xb, wqb, red);

    gemm_qkvf<<<1536, 256, 0, stream>>>(xb, wqb, y, qd, ksum, kvd, lkvd);

    scale_weights<<<1152, 256, 0, stream>>>(w1, w2, kvd, lkvd, w1s, w2s);

    norm_q<<<16384, 768, 0, stream>>>(qd, ksum, qn);

    gemm_proj<<<1536, 256, 0, stream>>>(
        qn, w1s, b1, out, w2s, b2, out + 12582912);
}